// Round 8
// baseline (119.647 us; speedup 1.0000x reference)
//
#include <hip/hip_runtime.h>
#include <stdint.h>
#include <stddef.h>

// ClusteredPrototypeLoss — MI355X, round 8.
// Revert to round-6 structure (measured best, 109.7us) + bit-exact 2-proto
// update kernel (halves its L2 traffic & block count).
// 8 launches: sampler -> (W -> U)x3 -> loss(+final-W +argmin +finalize).

namespace {

constexpr int kB = 2;
constexpr int kNT = 1000, kNP = 125, kNZ = 1000;
constexpr float kTempT = 0.033f, kTempS = 0.066f;
constexpr double kSig2 = (128.0 / 2.355) * (128.0 / 2.355);
constexpr float kTwoSig2 = (float)(2.0 * kSig2);

// ---------------- host: replicate np.random.default_rng(0).integers(0,8,6) ----------------
struct Pcg64 {
  __uint128_t state, inc;
  static __uint128_t mult() {
    return (((__uint128_t)2549297995355413924ULL) << 64) | 4865540595714422341ULL;
  }
  void step() { state = state * mult() + inc; }
  void seed(__uint128_t initstate, __uint128_t initseq) {
    state = 0; inc = (initseq << 1) | 1; step(); state += initstate; step();
  }
  uint64_t next64() {
    step();
    uint64_t xo = (uint64_t)(state >> 64) ^ (uint64_t)state;
    unsigned rot = (unsigned)((uint64_t)(state >> 122) & 63u);
    return (xo >> rot) | (xo << ((64u - rot) & 63u));
  }
};

static inline uint32_t ss_hashmix(uint32_t v, uint32_t& hc) {
  v ^= hc; hc *= 0x931e8875u; v *= hc; v ^= v >> 16; return v;
}
static inline uint32_t ss_mix(uint32_t x, uint32_t y) {
  uint32_t r = (0xca01f9ddu * x) ^ (0x4973f715u * y);
  r ^= r >> 16; return r;
}

static void numpy_jitter_seed0(int jit[6]) {
  uint32_t pool[4];
  uint32_t hc = 0x43b0d7e5u;  // INIT_A
  for (int i = 0; i < 4; ++i) pool[i] = ss_hashmix(0u, hc);
  for (int s = 0; s < 4; ++s)
    for (int d = 0; d < 4; ++d)
      if (s != d) pool[d] = ss_mix(pool[d], ss_hashmix(pool[s], hc));
  uint32_t w32[8];
  uint32_t hb = 0x8b51f9ddu;  // INIT_B
  for (int i = 0; i < 8; ++i) {
    uint32_t dv = pool[i & 3];
    dv ^= hb; hb *= 0x58f38dedu; dv *= hb; dv ^= dv >> 16;
    w32[i] = dv;
  }
  uint64_t w64[4];
  for (int i = 0; i < 4; ++i)
    w64[i] = (uint64_t)w32[2 * i] | ((uint64_t)w32[2 * i + 1] << 32);
  Pcg64 rng;
  rng.seed((((__uint128_t)w64[0]) << 64) | w64[1],
           (((__uint128_t)w64[2]) << 64) | w64[3]);
  for (int i = 0; i < 6; ++i) jit[i] = (int)(rng.next64() & 7ULL);
}

// ---------------- device helpers ----------------

struct AxisTap { int a, b; float w; };

__device__ inline AxisTap axis_tap(int i, float sc, int S) {
  float src = (i + 0.5f) * sc - 0.5f;
  float f = floorf(src);
  float w = src - f;
  int a = (int)f; a = a < 0 ? 0 : (a > S - 1 ? S - 1 : a);
  int b = (a + 1 > S - 1) ? S - 1 : a + 1;
  return {a, b, w};
}

__device__ inline float trilerp_vals(float v000, float v100, float v010, float v110,
                                     float v001, float v101, float v011, float v111,
                                     float w0, float w1, float w2) {
  float t00 = v000 * (1.0f - w0) + v100 * w0;
  float t10 = v010 * (1.0f - w0) + v110 * w0;
  float t01 = v001 * (1.0f - w0) + v101 * w0;
  float t11 = v011 * (1.0f - w0) + v111 * w0;
  float u0 = t00 * (1.0f - w1) + t10 * w1;
  float u1 = t01 * (1.0f - w1) + t11 * w1;
  return u0 * (1.0f - w2) + u1 * w2;
}

__device__ inline void coord_exact(int i, int j, int k,
                                   float sc0, float sc1, float sc2,
                                   int s0, int s1, int s2, int S0, int S1, int S2,
                                   float& c0o, float& c1o, float& c2o) {
#pragma clang fp contract(off)
  float src0 = (i + 0.5f) * sc0 - 0.5f;
  float f0 = floorf(src0); float w0 = src0 - f0;
  int a0 = (int)f0; a0 = a0 < 0 ? 0 : (a0 > S0 - 1 ? S0 - 1 : a0);
  int b0 = (a0 + 1 > S0 - 1) ? S0 - 1 : a0 + 1;

  float src1 = (j + 0.5f) * sc1 - 0.5f;
  float f1 = floorf(src1); float w1 = src1 - f1;
  int a1 = (int)f1; a1 = a1 < 0 ? 0 : (a1 > S1 - 1 ? S1 - 1 : a1);
  int b1 = (a1 + 1 > S1 - 1) ? S1 - 1 : a1 + 1;

  float src2 = (k + 0.5f) * sc2 - 0.5f;
  float f2 = floorf(src2); float w2 = src2 - f2;
  int a2 = (int)f2; a2 = a2 < 0 ? 0 : (a2 > S2 - 1 ? S2 - 1 : a2);
  int b2 = (a2 + 1 > S2 - 1) ? S2 - 1 : a2 + 1;

  float v0 = (float)(s0 + a0), v1 = (float)(s0 + b0);
  float c0 = v0 * (1.0f - w0) + v1 * w0;
  c0 = c0 * (1.0f - w1) + c0 * w1;
  c0 = c0 * (1.0f - w2) + c0 * w2;

  float g0 = (float)(s1 + a1), g1 = (float)(s1 + b1);
  float gA = g0 * (1.0f - w0) + g0 * w0;
  float gB = g1 * (1.0f - w0) + g1 * w0;
  float c1 = gA * (1.0f - w1) + gB * w1;
  c1 = c1 * (1.0f - w2) + c1 * w2;

  float h0 = (float)(s2 + a2), h1 = (float)(s2 + b2);
  float hA = h0 * (1.0f - w0) + h0 * w0;
  float hB = h1 * (1.0f - w0) + h1 * w0;
  hA = hA * (1.0f - w1) + hA * w1;
  hB = hB * (1.0f - w1) + hB * w1;
  float c2 = hA * (1.0f - w2) + hB * w2;

  c0o = c0; c1o = c1; c2o = c2;
}

__device__ inline void argmin_rowT(float zx, float zy, float zz,
                                   const float* ct0, const float* ct1, const float* ct2,
                                   int lane, float& best, int& bidx) {
#pragma clang fp contract(off)
  best = 3.4e38f; bidx = 0x7fffffff;
  for (int i = 0; i < 16; ++i) {
    float dx = zx - ct0[i * 64 + lane];
    float dy = zy - ct1[i * 64 + lane];
    float dz = zz - ct2[i * 64 + lane];
    float q0 = dx * dx, q1 = dy * dy, q2 = dz * dz;
    float d = sqrtf((q0 + q1) + q2);
    int n = lane * 16 + i;
    if (d < best) { best = d; bidx = n; }
  }
  for (int o = 32; o; o >>= 1) {
    float ob = __shfl_xor(best, o, 64);
    int oi = __shfl_xor(bidx, o, 64);
    if (ob < best || (ob == best && oi < bidx)) { best = ob; bidx = oi; }
  }
}

// ---------------- kernels ----------------

// Fused sampler — round-6 verbatim (TLB-friendly 16ch/wave gather).
__global__ __launch_bounds__(256) void sampler_kernel(
    const float* __restrict__ emb_t, const float* __restrict__ emb_s,
    float* __restrict__ EMB_TS, float* __restrict__ EMB_TN,
    float* __restrict__ EMB_ZN, float* __restrict__ EMB_PN,
    float* __restrict__ COORD_P, float* __restrict__ COORD_T,
    float* __restrict__ COORD_Z, int* __restrict__ cnt,
    int j0, int j2, int j4, int S0, int S1, int S2,
    float scZ0, float scZ1, float scZ2) {
  if (blockIdx.x == 0 && threadIdx.x == 0) atomicExch(cnt, 0);
  __shared__ float tile[4][20][64];
  __shared__ int zg[20];

  int blk = blockIdx.x;
  int fam, b, i, jj, Kb;
  float sc0, sc1, sc2; int Sa0, Sa1, Sa2, o0, o1, o2;
  const float* src;
  if (blk < 50) {
    fam = 0; int r = blk; b = r / 25; r %= 25; i = r / 5; jj = r % 5; Kb = 5;
    sc0 = sc1 = sc2 = 16.0f; Sa0 = Sa1 = Sa2 = 80; o0 = o1 = o2 = 0; src = emb_t;
  } else if (blk < 250) {
    fam = 1; int r = blk - 50; b = r / 100; r %= 100; i = r / 10; jj = r % 10; Kb = 10;
    sc0 = sc1 = sc2 = 8.0f; Sa0 = Sa1 = Sa2 = 80; o0 = o1 = o2 = 0; src = emb_t;
  } else {
    fam = 2; int r = blk - 250; b = r / 100; r %= 100; i = r / 10; jj = r % 10; Kb = 10;
    sc0 = scZ0; sc1 = scZ1; sc2 = scZ2; Sa0 = S0; Sa1 = S1; Sa2 = S2;
    o0 = j0; o1 = j2; o2 = j4; src = emb_s;
  }
  AxisTap t0 = axis_tap(i, sc0, Sa0);
  AxisTap t1 = axis_tap(jj, sc1, Sa1);
  if (threadIdx.x < (unsigned)(2 * Kb)) {
    AxisTap tz = axis_tap((int)threadIdx.x >> 1, sc2, Sa2);
    zg[threadIdx.x] = o2 + ((threadIdx.x & 1) ? tz.b : tz.a);
  }
  __syncthreads();
  int wv = threadIdx.x >> 6, lane = threadIdx.x & 63;
  {
    int dx = wv >> 1, dy = wv & 1;
    int x = o0 + (dx ? t0.b : t0.a);
    int y = o1 + (dy ? t1.b : t1.a);
    int chq = lane & 15, zseg = lane >> 4;
    size_t xyoff = ((size_t)x * 80 + y) * 80;
    for (int chg = 0; chg < 4; ++chg) {
      int ch = chg * 16 + chq;
      const float* row = src + ((size_t)(b * 64 + ch)) * 512000 + xyoff;
      for (int zi = zseg; zi < 2 * Kb; zi += 4) tile[wv][zi][ch] = row[zg[zi]];
    }
  }
  __syncthreads();

  for (int k = wv; k < Kb; k += 4) {
    AxisTap t2 = axis_tap(k, sc2, Sa2);
    int z0 = 2 * k, z1 = 2 * k + 1;
    float v000 = tile[0][z0][lane], v001 = tile[0][z1][lane];
    float v010 = tile[1][z0][lane], v011 = tile[1][z1][lane];
    float v100 = tile[2][z0][lane], v101 = tile[2][z1][lane];
    float v110 = tile[3][z0][lane], v111 = tile[3][z1][lane];
    float x = trilerp_vals(v000, v100, v010, v110, v001, v101, v011, v111,
                           t0.w, t1.w, t2.w);
    float ss = x * x;
    for (int o = 32; o; o >>= 1) ss += __shfl_xor(ss, o, 64);
    float nrm = sqrtf(ss);
    float xn = x / fmaxf(nrm, 1e-12f);

    if (fam == 0) {
      int p = (i * 5 + jj) * 5 + k;
      EMB_PN[((size_t)b * kNP + p) * 64 + lane] = xn;
      if (lane == 0) {
        float c0, c1, c2;
        coord_exact(i, jj, k, 16.0f, 16.0f, 16.0f, 0, 0, 0, 80, 80, 80, c0, c1, c2);
        size_t o3 = ((size_t)b * kNP + p) * 3;
        COORD_P[o3] = c0; COORD_P[o3 + 1] = c1; COORD_P[o3 + 2] = c2;
      }
    } else if (fam == 1) {
      int n = (i * 10 + jj) * 10 + k;
      EMB_TS[((size_t)b * kNT + n) * 64 + lane] = x;
      EMB_TN[((size_t)b * kNT + n) * 64 + lane] = xn;
      if (lane == 0) {
        float c0, c1, c2;
        coord_exact(i, jj, k, 8.0f, 8.0f, 8.0f, 0, 0, 0, 80, 80, 80, c0, c1, c2);
        size_t o3 = ((size_t)b * kNT + n) * 3;
        COORD_T[o3] = c0; COORD_T[o3 + 1] = c1; COORD_T[o3 + 2] = c2;
      }
    } else {
      int n = (i * 10 + jj) * 10 + k;
      EMB_ZN[((size_t)b * kNZ + n) * 64 + lane] = xn;
      if (lane == 0) {
        float c0, c1, c2;
        coord_exact(i, jj, k, scZ0, scZ1, scZ2, j0, j2, j4, S0, S1, S2, c0, c1, c2);
        size_t o3 = ((size_t)b * kNZ + n) * 3;
        COORD_Z[o3] = c0; COORD_Z[o3 + 1] = c1; COORD_Z[o3 + 2] = c2;
      }
    }
  }
}

// W kernel — round-6 verbatim (250 blocks x 8 rows).
__global__ __launch_bounds__(256) void wkernel(
    const float* __restrict__ embtn, const float* __restrict__ embpn,
    const float* __restrict__ coordt, const float* __restrict__ coordp,
    float* __restrict__ W) {
  __shared__ float pnT[64 * 129];
  __shared__ float en[8][64];
  __shared__ float cpx[128], cpy[128], cpz[128];
  int b = blockIdx.x / 125, grp = blockIdx.x % 125;
  for (int t = threadIdx.x; t < kNP * 64; t += 256) {
    int p = t >> 6, c = t & 63;
    pnT[c * 129 + p] = embpn[((size_t)b * kNP + p) * 64 + c];
  }
  for (int t = threadIdx.x; t < kNP; t += 256) {
    cpx[t] = coordp[((size_t)b * kNP + t) * 3 + 0];
    cpy[t] = coordp[((size_t)b * kNP + t) * 3 + 1];
    cpz[t] = coordp[((size_t)b * kNP + t) * 3 + 2];
  }
  for (int t = threadIdx.x; t < 8 * 64; t += 256) {
    int r = t >> 6, c = t & 63;
    en[r][c] = embtn[((size_t)b * kNT + grp * 8 + r) * 64 + c];
  }
  __syncthreads();
  int wv = threadIdx.x >> 6, lane = threadIdx.x & 63;
  bool v1 = lane < (kNP - 64);
  for (int rr = wv; rr < 8; rr += 4) {
    int n = grp * 8 + rr;
    float a0 = 0.f, a1 = 0.f;
#pragma unroll
    for (int c = 0; c < 64; ++c) {
      float ec = en[rr][c];
      a0 += ec * pnT[c * 129 + lane];
      a1 += ec * pnT[c * 129 + 64 + lane];
    }
    float l0 = a0 / kTempT;
    float l1 = v1 ? (a1 / kTempT) : -3.4e38f;
    float m = fmaxf(l0, l1);
    for (int o = 32; o; o >>= 1) m = fmaxf(m, __shfl_xor(m, o, 64));
    float e0 = expf(l0 - m);
    float e1 = v1 ? expf(l1 - m) : 0.f;
    float s = e0 + e1;
    for (int o = 32; o; o >>= 1) s += __shfl_xor(s, o, 64);
    float tx = coordt[((size_t)b * kNT + n) * 3 + 0];
    float ty = coordt[((size_t)b * kNT + n) * 3 + 1];
    float tz = coordt[((size_t)b * kNT + n) * 3 + 2];
    {
      float dx = tx - cpx[lane], dy = ty - cpy[lane], dz = tz - cpz[lane];
      float d2 = dx * dx + dy * dy + dz * dz;
      W[((size_t)b * kNT + n) * kNP + lane] = (e0 / s) * expf(-d2 / kTwoSig2);
    }
    if (v1) {
      float dx = tx - cpx[64 + lane], dy = ty - cpy[64 + lane], dz = tz - cpz[64 + lane];
      float d2 = dx * dx + dy * dy + dz * dz;
      W[((size_t)b * kNT + n) * kNP + 64 + lane] = (e1 / s) * expf(-d2 / kTwoSig2);
    }
  }
}

// Update: 2 prototypes per block (two INDEPENDENT accumulation chains, each
// bit-identical to round-6's single-p chain; e/cc loads shared). Grid 126.
__global__ __launch_bounds__(256) void update_kernel(
    const float* __restrict__ W, const float* __restrict__ embts,
    const float* __restrict__ coordt, float* __restrict__ embpn,
    float* __restrict__ coordp) {
  int b = blockIdx.x / 63, j = blockIdx.x % 63;
  int p1 = j, p2 = j + 63;
  bool has2 = p2 < kNP;
  int wv = threadIdx.x >> 6, lane = threadIdx.x & 63;
  __shared__ float wcol[2][kNT];
  const float* Wb1 = W + ((size_t)b * kNT) * kNP + p1;
  const float* Wb2 = W + ((size_t)b * kNT) * kNP + p2;
  for (int n = threadIdx.x; n < kNT; n += 256) {
    wcol[0][n] = Wb1[(size_t)n * kNP];
    wcol[1][n] = has2 ? Wb2[(size_t)n * kNP] : 0.f;
  }
  __syncthreads();

  float accE1 = 0.f, accC1 = 0.f, accD1 = 0.f;
  float accE2 = 0.f, accC2 = 0.f, accD2 = 0.f;
  const float* Eb = embts + ((size_t)b * kNT) * 64;
  const float* Cb = coordt + ((size_t)b * kNT) * 3;
  for (int n0 = wv * 250; n0 < (wv + 1) * 250; n0 += 10) {
    float w1[10], w2[10], e[10], cc[10];
#pragma unroll
    for (int u = 0; u < 10; ++u) w1[u] = wcol[0][n0 + u];
#pragma unroll
    for (int u = 0; u < 10; ++u) w2[u] = wcol[1][n0 + u];
#pragma unroll
    for (int u = 0; u < 10; ++u) e[u] = Eb[(size_t)(n0 + u) * 64 + lane];
    if (lane < 3) {
#pragma unroll
      for (int u = 0; u < 10; ++u) cc[u] = Cb[(size_t)(n0 + u) * 3 + lane];
    }
#pragma unroll
    for (int u = 0; u < 10; ++u) {
      accD1 += w1[u];
      accE1 += w1[u] * e[u];
      if (lane < 3) accC1 += w1[u] * cc[u];
    }
#pragma unroll
    for (int u = 0; u < 10; ++u) {
      accD2 += w2[u];
      accE2 += w2[u] * e[u];
      if (lane < 3) accC2 += w2[u] * cc[u];
    }
  }
  __shared__ float sE[2][4][64];
  __shared__ float sC[2][4][3];
  __shared__ float sD[2][4];
  sE[0][wv][lane] = accE1; sE[1][wv][lane] = accE2;
  if (lane < 3) { sC[0][wv][lane] = accC1; sC[1][wv][lane] = accC2; }
  if (lane == 0) { sD[0][wv] = accD1; sD[1][wv] = accD2; }
  __syncthreads();
  if (threadIdx.x < 128) {
    int which = wv;                 // wave 0 -> p1, wave 1 -> p2
    int p = which ? p2 : p1;
    if (!which || has2) {
      float d = sD[which][0] + sD[which][1] + sD[which][2] + sD[which][3];
      float x = (sE[which][0][lane] + sE[which][1][lane] +
                 sE[which][2][lane] + sE[which][3][lane]) / d;
      float ss = x * x;
      for (int o = 32; o; o >>= 1) ss += __shfl_xor(ss, o, 64);
      float nrm = sqrtf(ss);
      embpn[((size_t)b * kNP + p) * 64 + lane] = x / fmaxf(nrm, 1e-12f);
      if (lane < 3) {
        float cc2 = sC[which][0][lane] + sC[which][1][lane] +
                    sC[which][2][lane] + sC[which][3][lane];
        coordp[((size_t)b * kNP + p) * 3 + lane] = cc2 / d;
      }
    }
  }
}

// Loss — round-6 verbatim (fused argmin + final-W recompute + finalize).
__global__ __launch_bounds__(256) void loss_kernel(
    const float* __restrict__ embzn, const float* __restrict__ embtn,
    const float* __restrict__ embpn, const float* __restrict__ coordz,
    const float* __restrict__ coordt, const float* __restrict__ coordp,
    float* __restrict__ partials, int* __restrict__ counter,
    float* __restrict__ out) {
  __shared__ float pnT[64 * 129];
  __shared__ float ctT0[1024], ctT1[1024], ctT2[1024];
  __shared__ float en[4][64];
  __shared__ float cpx[128], cpy[128], cpz[128];
  __shared__ float sR[4], sM[4];
  int b = blockIdx.x / 250, chunk = blockIdx.x % 250;
  for (int t = threadIdx.x; t < kNP * 64; t += 256) {
    int p = t >> 6, c = t & 63;
    pnT[c * 129 + p] = embpn[((size_t)b * kNP + p) * 64 + c];
  }
  for (int t = threadIdx.x; t < kNP; t += 256) {
    cpx[t] = coordp[((size_t)b * kNP + t) * 3 + 0];
    cpy[t] = coordp[((size_t)b * kNP + t) * 3 + 1];
    cpz[t] = coordp[((size_t)b * kNP + t) * 3 + 2];
  }
  for (int n = threadIdx.x; n < 1024; n += 256) {
    int pos = (n & 15) * 64 + (n >> 4);
    if (n < 1000) {
      ctT0[pos] = coordt[((size_t)b * kNT + n) * 3 + 0];
      ctT1[pos] = coordt[((size_t)b * kNT + n) * 3 + 1];
      ctT2[pos] = coordt[((size_t)b * kNT + n) * 3 + 2];
    } else {
      ctT0[pos] = 3.4e38f; ctT1[pos] = 3.4e38f; ctT2[pos] = 3.4e38f;
    }
  }
  {
    int r = threadIdx.x >> 6, c = threadIdx.x & 63;
    en[r][c] = embzn[((size_t)b * kNZ + chunk * 4 + r) * 64 + c];
  }
  __syncthreads();
  int wv = threadIdx.x >> 6, lane = threadIdx.x & 63;
  bool v1 = lane < (kNP - 64);
  int z = chunk * 4 + wv;

  float zx = coordz[((size_t)b * kNZ + z) * 3 + 0];
  float zy = coordz[((size_t)b * kNZ + z) * 3 + 1];
  float zzv = coordz[((size_t)b * kNZ + z) * 3 + 2];
  float best; int id;
  argmin_rowT(zx, zy, zzv, ctT0, ctT1, ctT2, lane, best, id);
  float msk = (best <= 4.0f) ? 1.0f : 0.0f;

  float a0 = 0.f, a1 = 0.f;
#pragma unroll
  for (int c = 0; c < 64; ++c) {
    float ec = en[wv][c];
    a0 += ec * pnT[c * 129 + lane];
    a1 += ec * pnT[c * 129 + 64 + lane];
  }
  float l0 = a0 / kTempS;
  float l1 = v1 ? (a1 / kTempS) : -3.4e38f;
  float m = fmaxf(l0, l1);
  for (int o = 32; o; o >>= 1) m = fmaxf(m, __shfl_xor(m, o, 64));
  float e0 = expf(l0 - m), e1 = v1 ? expf(l1 - m) : 0.f;
  float s = e0 + e1;
  for (int o = 32; o; o >>= 1) s += __shfl_xor(s, o, 64);
  float lt0 = fminf(fmaxf(logf(e0 / s + 1e-16f), -1000.0f), 0.0f);
  float lt1 = 0.f;
  if (v1) lt1 = fminf(fmaxf(logf(e1 / s + 1e-16f), -1000.0f), 0.0f);

  float ev = embtn[((size_t)b * kNT + id) * 64 + lane];
  float wa0 = 0.f, wa1 = 0.f;
#pragma unroll
  for (int c = 0; c < 64; ++c) {
    float ec = __shfl(ev, c, 64);
    wa0 += ec * pnT[c * 129 + lane];
    wa1 += ec * pnT[c * 129 + 64 + lane];
  }
  float wl0 = wa0 / kTempT;
  float wl1 = v1 ? (wa1 / kTempT) : -3.4e38f;
  float wm = fmaxf(wl0, wl1);
  for (int o = 32; o; o >>= 1) wm = fmaxf(wm, __shfl_xor(wm, o, 64));
  float we0 = expf(wl0 - wm);
  float we1 = v1 ? expf(wl1 - wm) : 0.f;
  float wsum = we0 + we1;
  for (int o = 32; o; o >>= 1) wsum += __shfl_xor(wsum, o, 64);
  int pos = (id & 15) * 64 + (id >> 4);
  float tx = ctT0[pos], ty = ctT1[pos], tz = ctT2[pos];
  float W0, W1 = 0.f;
  {
    float dx = tx - cpx[lane], dy = ty - cpy[lane], dz = tz - cpz[lane];
    float d2 = dx * dx + dy * dy + dz * dz;
    W0 = (we0 / wsum) * expf(-d2 / kTwoSig2);
  }
  if (v1) {
    float dx = tx - cpx[64 + lane], dy = ty - cpy[64 + lane], dz = tz - cpz[64 + lane];
    float d2 = dx * dx + dy * dy + dz * dz;
    W1 = (we1 / wsum) * expf(-d2 / kTwoSig2);
  }

  float r = W0 * lt0;
  if (v1) r += W1 * lt1;
  for (int o = 32; o; o >>= 1) r += __shfl_xor(r, o, 64);
  if (lane == 0) { sR[wv] = -(r * msk); sM[wv] = msk; }
  __syncthreads();
  if (threadIdx.x == 0) {
    partials[(size_t)(b * 250 + chunk) * 2 + 0] = sR[0] + sR[1] + sR[2] + sR[3];
    partials[(size_t)(b * 250 + chunk) * 2 + 1] = sM[0] + sM[1] + sM[2] + sM[3];
  }
  __syncthreads();
  __shared__ int isLast;
  if (threadIdx.x == 0) {
    __threadfence();
    isLast = (atomicAdd(counter, 1) == 499) ? 1 : 0;
  }
  __syncthreads();
  if (isLast && threadIdx.x < 64) {
    __threadfence();
    float loss = 0.f;
    for (int bb = 0; bb < kB; ++bb) {
      float rr = 0.f, mm = 0.f;
      for (int c2 = threadIdx.x; c2 < 250; c2 += 64) {
        rr += partials[(size_t)(bb * 250 + c2) * 2 + 0];
        mm += partials[(size_t)(bb * 250 + c2) * 2 + 1];
      }
      for (int o = 32; o; o >>= 1) {
        rr += __shfl_xor(rr, o, 64);
        mm += __shfl_xor(mm, o, 64);
      }
      loss += rr / mm;
    }
    if (threadIdx.x == 0) out[0] = loss * 0.5f;
  }
}

}  // namespace

extern "C" void kernel_launch(void* const* d_in, const int* in_sizes, int n_in,
                              void* d_out, int out_size, void* d_ws, size_t ws_size,
                              hipStream_t stream) {
  (void)in_sizes; (void)n_in; (void)out_size; (void)ws_size;
  const float* emb_s = (const float*)d_in[0];
  const float* emb_t = (const float*)d_in[1];

  float* ws = (float*)d_ws;
  float* EMB_TS  = ws + 0;       // 2*1000*64
  float* EMB_TN  = ws + 128000;  // 2*1000*64
  float* EMB_ZN  = ws + 256000;  // 2*1000*64
  float* EMB_PN  = ws + 384000;  // 2*125*64
  float* COORD_P = ws + 400000;  // 752
  float* COORD_T = ws + 400752;  // 6,000
  float* COORD_Z = ws + 406752;  // 6,000
  float* Wbuf    = ws + 412752;  // 250,000
  float* PART    = ws + 662752;  // 1,000
  int*   CNT     = (int*)(ws + 663752);

  int jit[6];
  numpy_jitter_seed0(jit);
  int S0 = 80 - jit[0] - jit[1];
  int S1 = 80 - jit[2] - jit[3];
  int S2 = 80 - jit[4] - jit[5];
  float scZ0 = (float)(S0 / 10.0);
  float scZ1 = (float)(S1 / 10.0);
  float scZ2 = (float)(S2 / 10.0);

  // 1. fused sampling (gather + trilerp + norm + coords; resets counter)
  sampler_kernel<<<450, 256, 0, stream>>>(
      emb_t, emb_s, EMB_TS, EMB_TN, EMB_ZN, EMB_PN, COORD_P, COORD_T, COORD_Z,
      CNT, jit[0], jit[2], jit[4], S0, S1, S2, scZ0, scZ1, scZ2);

  // 2-7. three clustering iterations
  for (int it = 0; it < 3; ++it) {
    wkernel<<<250, 256, 0, stream>>>(EMB_TN, EMB_PN, COORD_T, COORD_P, Wbuf);
    update_kernel<<<126, 256, 0, stream>>>(Wbuf, EMB_TS, COORD_T, EMB_PN, COORD_P);
  }

  // 8. loss (+final-W recompute +argmin +finalize)
  loss_kernel<<<500, 256, 0, stream>>>(EMB_ZN, EMB_TN, EMB_PN, COORD_Z, COORD_T,
                                       COORD_P, PART, CNT, (float*)d_out);
}

// Round 9
// 109.833 us; speedup vs baseline: 1.0894x; 1.0894x over previous
//
#include <hip/hip_runtime.h>
#include <stdint.h>
#include <stddef.h>

// ClusteredPrototypeLoss — MI355X, round 9 = round 6 verbatim (measured best:
// 109.7us). Rounds 7/8 "improvements" both regressed (latency-bound, not
// traffic-bound); reverting per methodology.
// 8 launches: sampler -> (W -> U)x3 -> loss(+final-W +argmin +finalize).

namespace {

constexpr int kB = 2;
constexpr int kNT = 1000, kNP = 125, kNZ = 1000;
constexpr float kTempT = 0.033f, kTempS = 0.066f;
constexpr double kSig2 = (128.0 / 2.355) * (128.0 / 2.355);
constexpr float kTwoSig2 = (float)(2.0 * kSig2);

// ---------------- host: replicate np.random.default_rng(0).integers(0,8,6) ----------------
struct Pcg64 {
  __uint128_t state, inc;
  static __uint128_t mult() {
    return (((__uint128_t)2549297995355413924ULL) << 64) | 4865540595714422341ULL;
  }
  void step() { state = state * mult() + inc; }
  void seed(__uint128_t initstate, __uint128_t initseq) {
    state = 0; inc = (initseq << 1) | 1; step(); state += initstate; step();
  }
  uint64_t next64() {
    step();
    uint64_t xo = (uint64_t)(state >> 64) ^ (uint64_t)state;
    unsigned rot = (unsigned)((uint64_t)(state >> 122) & 63u);
    return (xo >> rot) | (xo << ((64u - rot) & 63u));
  }
};

static inline uint32_t ss_hashmix(uint32_t v, uint32_t& hc) {
  v ^= hc; hc *= 0x931e8875u; v *= hc; v ^= v >> 16; return v;
}
static inline uint32_t ss_mix(uint32_t x, uint32_t y) {
  uint32_t r = (0xca01f9ddu * x) ^ (0x4973f715u * y);
  r ^= r >> 16; return r;
}

static void numpy_jitter_seed0(int jit[6]) {
  uint32_t pool[4];
  uint32_t hc = 0x43b0d7e5u;  // INIT_A
  for (int i = 0; i < 4; ++i) pool[i] = ss_hashmix(0u, hc);
  for (int s = 0; s < 4; ++s)
    for (int d = 0; d < 4; ++d)
      if (s != d) pool[d] = ss_mix(pool[d], ss_hashmix(pool[s], hc));
  uint32_t w32[8];
  uint32_t hb = 0x8b51f9ddu;  // INIT_B
  for (int i = 0; i < 8; ++i) {
    uint32_t dv = pool[i & 3];
    dv ^= hb; hb *= 0x58f38dedu; dv *= hb; dv ^= dv >> 16;
    w32[i] = dv;
  }
  uint64_t w64[4];
  for (int i = 0; i < 4; ++i)
    w64[i] = (uint64_t)w32[2 * i] | ((uint64_t)w32[2 * i + 1] << 32);
  Pcg64 rng;
  rng.seed((((__uint128_t)w64[0]) << 64) | w64[1],
           (((__uint128_t)w64[2]) << 64) | w64[3]);
  for (int i = 0; i < 6; ++i) jit[i] = (int)(rng.next64() & 7ULL);
}

// ---------------- device helpers ----------------

struct AxisTap { int a, b; float w; };

__device__ inline AxisTap axis_tap(int i, float sc, int S) {
  float src = (i + 0.5f) * sc - 0.5f;
  float f = floorf(src);
  float w = src - f;
  int a = (int)f; a = a < 0 ? 0 : (a > S - 1 ? S - 1 : a);
  int b = (a + 1 > S - 1) ? S - 1 : a + 1;
  return {a, b, w};
}

__device__ inline float trilerp_vals(float v000, float v100, float v010, float v110,
                                     float v001, float v101, float v011, float v111,
                                     float w0, float w1, float w2) {
  float t00 = v000 * (1.0f - w0) + v100 * w0;
  float t10 = v010 * (1.0f - w0) + v110 * w0;
  float t01 = v001 * (1.0f - w0) + v101 * w0;
  float t11 = v011 * (1.0f - w0) + v111 * w0;
  float u0 = t00 * (1.0f - w1) + t10 * w1;
  float u1 = t01 * (1.0f - w1) + t11 * w1;
  return u0 * (1.0f - w2) + u1 * w2;
}

__device__ inline void coord_exact(int i, int j, int k,
                                   float sc0, float sc1, float sc2,
                                   int s0, int s1, int s2, int S0, int S1, int S2,
                                   float& c0o, float& c1o, float& c2o) {
#pragma clang fp contract(off)
  float src0 = (i + 0.5f) * sc0 - 0.5f;
  float f0 = floorf(src0); float w0 = src0 - f0;
  int a0 = (int)f0; a0 = a0 < 0 ? 0 : (a0 > S0 - 1 ? S0 - 1 : a0);
  int b0 = (a0 + 1 > S0 - 1) ? S0 - 1 : a0 + 1;

  float src1 = (j + 0.5f) * sc1 - 0.5f;
  float f1 = floorf(src1); float w1 = src1 - f1;
  int a1 = (int)f1; a1 = a1 < 0 ? 0 : (a1 > S1 - 1 ? S1 - 1 : a1);
  int b1 = (a1 + 1 > S1 - 1) ? S1 - 1 : a1 + 1;

  float src2 = (k + 0.5f) * sc2 - 0.5f;
  float f2 = floorf(src2); float w2 = src2 - f2;
  int a2 = (int)f2; a2 = a2 < 0 ? 0 : (a2 > S2 - 1 ? S2 - 1 : a2);
  int b2 = (a2 + 1 > S2 - 1) ? S2 - 1 : a2 + 1;

  float v0 = (float)(s0 + a0), v1 = (float)(s0 + b0);
  float c0 = v0 * (1.0f - w0) + v1 * w0;
  c0 = c0 * (1.0f - w1) + c0 * w1;
  c0 = c0 * (1.0f - w2) + c0 * w2;

  float g0 = (float)(s1 + a1), g1 = (float)(s1 + b1);
  float gA = g0 * (1.0f - w0) + g0 * w0;
  float gB = g1 * (1.0f - w0) + g1 * w0;
  float c1 = gA * (1.0f - w1) + gB * w1;
  c1 = c1 * (1.0f - w2) + c1 * w2;

  float h0 = (float)(s2 + a2), h1 = (float)(s2 + b2);
  float hA = h0 * (1.0f - w0) + h0 * w0;
  float hB = h1 * (1.0f - w0) + h1 * w0;
  hA = hA * (1.0f - w1) + hA * w1;
  hB = hB * (1.0f - w1) + hB * w1;
  float c2 = hA * (1.0f - w2) + hB * w2;

  c0o = c0; c1o = c1; c2o = c2;
}

__device__ inline void argmin_rowT(float zx, float zy, float zz,
                                   const float* ct0, const float* ct1, const float* ct2,
                                   int lane, float& best, int& bidx) {
#pragma clang fp contract(off)
  best = 3.4e38f; bidx = 0x7fffffff;
  for (int i = 0; i < 16; ++i) {
    float dx = zx - ct0[i * 64 + lane];
    float dy = zy - ct1[i * 64 + lane];
    float dz = zz - ct2[i * 64 + lane];
    float q0 = dx * dx, q1 = dy * dy, q2 = dz * dz;
    float d = sqrtf((q0 + q1) + q2);
    int n = lane * 16 + i;
    if (d < best) { best = d; bidx = n; }
  }
  for (int o = 32; o; o >>= 1) {
    float ob = __shfl_xor(best, o, 64);
    int oi = __shfl_xor(bidx, o, 64);
    if (ob < best || (ob == best && oi < bidx)) { best = ob; bidx = oi; }
  }
}

// ---------------- kernels ----------------

// Fused sampler: 450 blocks. Block = (family, b, i, jj). TLB-friendly gather:
// each wave reads 16 channels x 4 z-segments per issue (16 pages/issue vs 64).
__global__ __launch_bounds__(256) void sampler_kernel(
    const float* __restrict__ emb_t, const float* __restrict__ emb_s,
    float* __restrict__ EMB_TS, float* __restrict__ EMB_TN,
    float* __restrict__ EMB_ZN, float* __restrict__ EMB_PN,
    float* __restrict__ COORD_P, float* __restrict__ COORD_T,
    float* __restrict__ COORD_Z, int* __restrict__ cnt,
    int j0, int j2, int j4, int S0, int S1, int S2,
    float scZ0, float scZ1, float scZ2) {
  if (blockIdx.x == 0 && threadIdx.x == 0) atomicExch(cnt, 0);
  __shared__ float tile[4][20][64];
  __shared__ int zg[20];

  int blk = blockIdx.x;
  int fam, b, i, jj, Kb;
  float sc0, sc1, sc2; int Sa0, Sa1, Sa2, o0, o1, o2;
  const float* src;
  if (blk < 50) {
    fam = 0; int r = blk; b = r / 25; r %= 25; i = r / 5; jj = r % 5; Kb = 5;
    sc0 = sc1 = sc2 = 16.0f; Sa0 = Sa1 = Sa2 = 80; o0 = o1 = o2 = 0; src = emb_t;
  } else if (blk < 250) {
    fam = 1; int r = blk - 50; b = r / 100; r %= 100; i = r / 10; jj = r % 10; Kb = 10;
    sc0 = sc1 = sc2 = 8.0f; Sa0 = Sa1 = Sa2 = 80; o0 = o1 = o2 = 0; src = emb_t;
  } else {
    fam = 2; int r = blk - 250; b = r / 100; r %= 100; i = r / 10; jj = r % 10; Kb = 10;
    sc0 = scZ0; sc1 = scZ1; sc2 = scZ2; Sa0 = S0; Sa1 = S1; Sa2 = S2;
    o0 = j0; o1 = j2; o2 = j4; src = emb_s;
  }
  AxisTap t0 = axis_tap(i, sc0, Sa0);
  AxisTap t1 = axis_tap(jj, sc1, Sa1);
  if (threadIdx.x < (unsigned)(2 * Kb)) {
    AxisTap tz = axis_tap((int)threadIdx.x >> 1, sc2, Sa2);
    zg[threadIdx.x] = o2 + ((threadIdx.x & 1) ? tz.b : tz.a);
  }
  __syncthreads();
  int wv = threadIdx.x >> 6, lane = threadIdx.x & 63;
  {
    int dx = wv >> 1, dy = wv & 1;
    int x = o0 + (dx ? t0.b : t0.a);
    int y = o1 + (dy ? t1.b : t1.a);
    int chq = lane & 15, zseg = lane >> 4;
    size_t xyoff = ((size_t)x * 80 + y) * 80;
    for (int chg = 0; chg < 4; ++chg) {
      int ch = chg * 16 + chq;
      const float* row = src + ((size_t)(b * 64 + ch)) * 512000 + xyoff;
      for (int zi = zseg; zi < 2 * Kb; zi += 4) tile[wv][zi][ch] = row[zg[zi]];
    }
  }
  __syncthreads();

  for (int k = wv; k < Kb; k += 4) {
    AxisTap t2 = axis_tap(k, sc2, Sa2);
    int z0 = 2 * k, z1 = 2 * k + 1;
    float v000 = tile[0][z0][lane], v001 = tile[0][z1][lane];
    float v010 = tile[1][z0][lane], v011 = tile[1][z1][lane];
    float v100 = tile[2][z0][lane], v101 = tile[2][z1][lane];
    float v110 = tile[3][z0][lane], v111 = tile[3][z1][lane];
    float x = trilerp_vals(v000, v100, v010, v110, v001, v101, v011, v111,
                           t0.w, t1.w, t2.w);
    float ss = x * x;
    for (int o = 32; o; o >>= 1) ss += __shfl_xor(ss, o, 64);
    float nrm = sqrtf(ss);
    float xn = x / fmaxf(nrm, 1e-12f);

    if (fam == 0) {
      int p = (i * 5 + jj) * 5 + k;
      EMB_PN[((size_t)b * kNP + p) * 64 + lane] = xn;
      if (lane == 0) {
        float c0, c1, c2;
        coord_exact(i, jj, k, 16.0f, 16.0f, 16.0f, 0, 0, 0, 80, 80, 80, c0, c1, c2);
        size_t o3 = ((size_t)b * kNP + p) * 3;
        COORD_P[o3] = c0; COORD_P[o3 + 1] = c1; COORD_P[o3 + 2] = c2;
      }
    } else if (fam == 1) {
      int n = (i * 10 + jj) * 10 + k;
      EMB_TS[((size_t)b * kNT + n) * 64 + lane] = x;
      EMB_TN[((size_t)b * kNT + n) * 64 + lane] = xn;
      if (lane == 0) {
        float c0, c1, c2;
        coord_exact(i, jj, k, 8.0f, 8.0f, 8.0f, 0, 0, 0, 80, 80, 80, c0, c1, c2);
        size_t o3 = ((size_t)b * kNT + n) * 3;
        COORD_T[o3] = c0; COORD_T[o3 + 1] = c1; COORD_T[o3 + 2] = c2;
      }
    } else {
      int n = (i * 10 + jj) * 10 + k;
      EMB_ZN[((size_t)b * kNZ + n) * 64 + lane] = xn;
      if (lane == 0) {
        float c0, c1, c2;
        coord_exact(i, jj, k, scZ0, scZ1, scZ2, j0, j2, j4, S0, S1, S2, c0, c1, c2);
        size_t o3 = ((size_t)b * kNZ + n) * 3;
        COORD_Z[o3] = c0; COORD_Z[o3 + 1] = c1; COORD_Z[o3 + 2] = c2;
      }
    }
  }
}

// W kernel: 250 blocks x 8 rows (2 rows/wave, sequential).
__global__ __launch_bounds__(256) void wkernel(
    const float* __restrict__ embtn, const float* __restrict__ embpn,
    const float* __restrict__ coordt, const float* __restrict__ coordp,
    float* __restrict__ W) {
  __shared__ float pnT[64 * 129];
  __shared__ float en[8][64];
  __shared__ float cpx[128], cpy[128], cpz[128];
  int b = blockIdx.x / 125, grp = blockIdx.x % 125;
  for (int t = threadIdx.x; t < kNP * 64; t += 256) {
    int p = t >> 6, c = t & 63;
    pnT[c * 129 + p] = embpn[((size_t)b * kNP + p) * 64 + c];
  }
  for (int t = threadIdx.x; t < kNP; t += 256) {
    cpx[t] = coordp[((size_t)b * kNP + t) * 3 + 0];
    cpy[t] = coordp[((size_t)b * kNP + t) * 3 + 1];
    cpz[t] = coordp[((size_t)b * kNP + t) * 3 + 2];
  }
  for (int t = threadIdx.x; t < 8 * 64; t += 256) {
    int r = t >> 6, c = t & 63;
    en[r][c] = embtn[((size_t)b * kNT + grp * 8 + r) * 64 + c];
  }
  __syncthreads();
  int wv = threadIdx.x >> 6, lane = threadIdx.x & 63;
  bool v1 = lane < (kNP - 64);
  for (int rr = wv; rr < 8; rr += 4) {
    int n = grp * 8 + rr;
    float a0 = 0.f, a1 = 0.f;
#pragma unroll
    for (int c = 0; c < 64; ++c) {
      float ec = en[rr][c];
      a0 += ec * pnT[c * 129 + lane];
      a1 += ec * pnT[c * 129 + 64 + lane];
    }
    float l0 = a0 / kTempT;
    float l1 = v1 ? (a1 / kTempT) : -3.4e38f;
    float m = fmaxf(l0, l1);
    for (int o = 32; o; o >>= 1) m = fmaxf(m, __shfl_xor(m, o, 64));
    float e0 = expf(l0 - m);
    float e1 = v1 ? expf(l1 - m) : 0.f;
    float s = e0 + e1;
    for (int o = 32; o; o >>= 1) s += __shfl_xor(s, o, 64);
    float tx = coordt[((size_t)b * kNT + n) * 3 + 0];
    float ty = coordt[((size_t)b * kNT + n) * 3 + 1];
    float tz = coordt[((size_t)b * kNT + n) * 3 + 2];
    {
      float dx = tx - cpx[lane], dy = ty - cpy[lane], dz = tz - cpz[lane];
      float d2 = dx * dx + dy * dy + dz * dz;
      W[((size_t)b * kNT + n) * kNP + lane] = (e0 / s) * expf(-d2 / kTwoSig2);
    }
    if (v1) {
      float dx = tx - cpx[64 + lane], dy = ty - cpy[64 + lane], dz = tz - cpz[64 + lane];
      float d2 = dx * dx + dy * dy + dz * dz;
      W[((size_t)b * kNT + n) * kNP + 64 + lane] = (e1 / s) * expf(-d2 / kTwoSig2);
    }
  }
}

// Update: W column staged in LDS; batched loads. 250 blocks.
__global__ __launch_bounds__(256) void update_kernel(
    const float* __restrict__ W, const float* __restrict__ embts,
    const float* __restrict__ coordt, float* __restrict__ embpn,
    float* __restrict__ coordp) {
  int bp = blockIdx.x; int b = bp / kNP; int p = bp % kNP;
  int wv = threadIdx.x >> 6, lane = threadIdx.x & 63;
  __shared__ float wcol[kNT];
  const float* Wb = W + ((size_t)b * kNT) * kNP + p;
  for (int n = threadIdx.x; n < kNT; n += 256) wcol[n] = Wb[(size_t)n * kNP];
  __syncthreads();

  float accE = 0.f, accC = 0.f, accD = 0.f;
  const float* Eb = embts + ((size_t)b * kNT) * 64;
  const float* Cb = coordt + ((size_t)b * kNT) * 3;
#pragma unroll 2
  for (int n0 = wv * 250; n0 < (wv + 1) * 250; n0 += 10) {
    float w[10], e[10], cc[10];
#pragma unroll
    for (int u = 0; u < 10; ++u) w[u] = wcol[n0 + u];
#pragma unroll
    for (int u = 0; u < 10; ++u) e[u] = Eb[(size_t)(n0 + u) * 64 + lane];
    if (lane < 3) {
#pragma unroll
      for (int u = 0; u < 10; ++u) cc[u] = Cb[(size_t)(n0 + u) * 3 + lane];
    }
#pragma unroll
    for (int u = 0; u < 10; ++u) {
      accD += w[u];
      accE += w[u] * e[u];
      if (lane < 3) accC += w[u] * cc[u];
    }
  }
  __shared__ float sE[4][64];
  __shared__ float sC[4][3];
  __shared__ float sD[4];
  sE[wv][lane] = accE;
  if (lane < 3) sC[wv][lane] = accC;
  if (lane == 0) sD[wv] = accD;
  __syncthreads();
  if (threadIdx.x < 64) {
    float d = sD[0] + sD[1] + sD[2] + sD[3];
    float x = (sE[0][lane] + sE[1][lane] + sE[2][lane] + sE[3][lane]) / d;
    float ss = x * x;
    for (int o = 32; o; o >>= 1) ss += __shfl_xor(ss, o, 64);
    float nrm = sqrtf(ss);
    embpn[((size_t)b * kNP + p) * 64 + lane] = x / fmaxf(nrm, 1e-12f);
    if (lane < 3) {
      float cc2 = sC[0][lane] + sC[1][lane] + sC[2][lane] + sC[3][lane];
      coordp[((size_t)b * kNP + p) * 3 + lane] = cc2 / d;
    }
  }
}

// Loss: 500 blocks, 1 z per wave; fused argmin + final-W recompute + finalize.
__global__ __launch_bounds__(256) void loss_kernel(
    const float* __restrict__ embzn, const float* __restrict__ embtn,
    const float* __restrict__ embpn, const float* __restrict__ coordz,
    const float* __restrict__ coordt, const float* __restrict__ coordp,
    float* __restrict__ partials, int* __restrict__ counter,
    float* __restrict__ out) {
  __shared__ float pnT[64 * 129];
  __shared__ float ctT0[1024], ctT1[1024], ctT2[1024];
  __shared__ float en[4][64];
  __shared__ float cpx[128], cpy[128], cpz[128];
  __shared__ float sR[4], sM[4];
  int b = blockIdx.x / 250, chunk = blockIdx.x % 250;
  for (int t = threadIdx.x; t < kNP * 64; t += 256) {
    int p = t >> 6, c = t & 63;
    pnT[c * 129 + p] = embpn[((size_t)b * kNP + p) * 64 + c];
  }
  for (int t = threadIdx.x; t < kNP; t += 256) {
    cpx[t] = coordp[((size_t)b * kNP + t) * 3 + 0];
    cpy[t] = coordp[((size_t)b * kNP + t) * 3 + 1];
    cpz[t] = coordp[((size_t)b * kNP + t) * 3 + 2];
  }
  for (int n = threadIdx.x; n < 1024; n += 256) {
    int pos = (n & 15) * 64 + (n >> 4);
    if (n < 1000) {
      ctT0[pos] = coordt[((size_t)b * kNT + n) * 3 + 0];
      ctT1[pos] = coordt[((size_t)b * kNT + n) * 3 + 1];
      ctT2[pos] = coordt[((size_t)b * kNT + n) * 3 + 2];
    } else {
      ctT0[pos] = 3.4e38f; ctT1[pos] = 3.4e38f; ctT2[pos] = 3.4e38f;
    }
  }
  {
    int r = threadIdx.x >> 6, c = threadIdx.x & 63;
    en[r][c] = embzn[((size_t)b * kNZ + chunk * 4 + r) * 64 + c];
  }
  __syncthreads();
  int wv = threadIdx.x >> 6, lane = threadIdx.x & 63;
  bool v1 = lane < (kNP - 64);
  int z = chunk * 4 + wv;

  float zx = coordz[((size_t)b * kNZ + z) * 3 + 0];
  float zy = coordz[((size_t)b * kNZ + z) * 3 + 1];
  float zzv = coordz[((size_t)b * kNZ + z) * 3 + 2];
  float best; int id;
  argmin_rowT(zx, zy, zzv, ctT0, ctT1, ctT2, lane, best, id);
  float msk = (best <= 4.0f) ? 1.0f : 0.0f;

  float a0 = 0.f, a1 = 0.f;
#pragma unroll
  for (int c = 0; c < 64; ++c) {
    float ec = en[wv][c];
    a0 += ec * pnT[c * 129 + lane];
    a1 += ec * pnT[c * 129 + 64 + lane];
  }
  float l0 = a0 / kTempS;
  float l1 = v1 ? (a1 / kTempS) : -3.4e38f;
  float m = fmaxf(l0, l1);
  for (int o = 32; o; o >>= 1) m = fmaxf(m, __shfl_xor(m, o, 64));
  float e0 = expf(l0 - m), e1 = v1 ? expf(l1 - m) : 0.f;
  float s = e0 + e1;
  for (int o = 32; o; o >>= 1) s += __shfl_xor(s, o, 64);
  float lt0 = fminf(fmaxf(logf(e0 / s + 1e-16f), -1000.0f), 0.0f);
  float lt1 = 0.f;
  if (v1) lt1 = fminf(fmaxf(logf(e1 / s + 1e-16f), -1000.0f), 0.0f);

  float ev = embtn[((size_t)b * kNT + id) * 64 + lane];
  float wa0 = 0.f, wa1 = 0.f;
#pragma unroll
  for (int c = 0; c < 64; ++c) {
    float ec = __shfl(ev, c, 64);
    wa0 += ec * pnT[c * 129 + lane];
    wa1 += ec * pnT[c * 129 + 64 + lane];
  }
  float wl0 = wa0 / kTempT;
  float wl1 = v1 ? (wa1 / kTempT) : -3.4e38f;
  float wm = fmaxf(wl0, wl1);
  for (int o = 32; o; o >>= 1) wm = fmaxf(wm, __shfl_xor(wm, o, 64));
  float we0 = expf(wl0 - wm);
  float we1 = v1 ? expf(wl1 - wm) : 0.f;
  float wsum = we0 + we1;
  for (int o = 32; o; o >>= 1) wsum += __shfl_xor(wsum, o, 64);
  int pos = (id & 15) * 64 + (id >> 4);
  float tx = ctT0[pos], ty = ctT1[pos], tz = ctT2[pos];
  float W0, W1 = 0.f;
  {
    float dx = tx - cpx[lane], dy = ty - cpy[lane], dz = tz - cpz[lane];
    float d2 = dx * dx + dy * dy + dz * dz;
    W0 = (we0 / wsum) * expf(-d2 / kTwoSig2);
  }
  if (v1) {
    float dx = tx - cpx[64 + lane], dy = ty - cpy[64 + lane], dz = tz - cpz[64 + lane];
    float d2 = dx * dx + dy * dy + dz * dz;
    W1 = (we1 / wsum) * expf(-d2 / kTwoSig2);
  }

  float r = W0 * lt0;
  if (v1) r += W1 * lt1;
  for (int o = 32; o; o >>= 1) r += __shfl_xor(r, o, 64);
  if (lane == 0) { sR[wv] = -(r * msk); sM[wv] = msk; }
  __syncthreads();
  if (threadIdx.x == 0) {
    partials[(size_t)(b * 250 + chunk) * 2 + 0] = sR[0] + sR[1] + sR[2] + sR[3];
    partials[(size_t)(b * 250 + chunk) * 2 + 1] = sM[0] + sM[1] + sM[2] + sM[3];
  }
  __syncthreads();
  __shared__ int isLast;
  if (threadIdx.x == 0) {
    __threadfence();
    isLast = (atomicAdd(counter, 1) == 499) ? 1 : 0;
  }
  __syncthreads();
  if (isLast && threadIdx.x < 64) {
    __threadfence();
    float loss = 0.f;
    for (int bb = 0; bb < kB; ++bb) {
      float rr = 0.f, mm = 0.f;
      for (int c2 = threadIdx.x; c2 < 250; c2 += 64) {
        rr += partials[(size_t)(bb * 250 + c2) * 2 + 0];
        mm += partials[(size_t)(bb * 250 + c2) * 2 + 1];
      }
      for (int o = 32; o; o >>= 1) {
        rr += __shfl_xor(rr, o, 64);
        mm += __shfl_xor(mm, o, 64);
      }
      loss += rr / mm;
    }
    if (threadIdx.x == 0) out[0] = loss * 0.5f;
  }
}

}  // namespace

extern "C" void kernel_launch(void* const* d_in, const int* in_sizes, int n_in,
                              void* d_out, int out_size, void* d_ws, size_t ws_size,
                              hipStream_t stream) {
  (void)in_sizes; (void)n_in; (void)out_size; (void)ws_size;
  const float* emb_s = (const float*)d_in[0];
  const float* emb_t = (const float*)d_in[1];

  float* ws = (float*)d_ws;
  float* EMB_TS  = ws + 0;       // 2*1000*64
  float* EMB_TN  = ws + 128000;  // 2*1000*64
  float* EMB_ZN  = ws + 256000;  // 2*1000*64
  float* EMB_PN  = ws + 384000;  // 2*125*64
  float* COORD_P = ws + 400000;  // 752
  float* COORD_T = ws + 400752;  // 6,000
  float* COORD_Z = ws + 406752;  // 6,000
  float* Wbuf    = ws + 412752;  // 250,000
  float* PART    = ws + 662752;  // 1,000
  int*   CNT     = (int*)(ws + 663752);

  int jit[6];
  numpy_jitter_seed0(jit);
  int S0 = 80 - jit[0] - jit[1];
  int S1 = 80 - jit[2] - jit[3];
  int S2 = 80 - jit[4] - jit[5];
  float scZ0 = (float)(S0 / 10.0);
  float scZ1 = (float)(S1 / 10.0);
  float scZ2 = (float)(S2 / 10.0);

  // 1. fused sampling (gather + trilerp + norm + coords; resets counter)
  sampler_kernel<<<450, 256, 0, stream>>>(
      emb_t, emb_s, EMB_TS, EMB_TN, EMB_ZN, EMB_PN, COORD_P, COORD_T, COORD_Z,
      CNT, jit[0], jit[2], jit[4], S0, S1, S2, scZ0, scZ1, scZ2);

  // 2-7. three clustering iterations
  for (int it = 0; it < 3; ++it) {
    wkernel<<<250, 256, 0, stream>>>(EMB_TN, EMB_PN, COORD_T, COORD_P, Wbuf);
    update_kernel<<<250, 256, 0, stream>>>(Wbuf, EMB_TS, COORD_T, EMB_PN, COORD_P);
  }

  // 8. loss (+final-W recompute +argmin +finalize)
  loss_kernel<<<500, 256, 0, stream>>>(EMB_ZN, EMB_TN, EMB_PN, COORD_Z, COORD_T,
                                       COORD_P, PART, CNT, (float*)d_out);
}